// Round 2
// baseline (296.395 us; speedup 1.0000x reference)
//
#include <hip/hip_runtime.h>

// Problem constants (from reference): N=65536 nodes, D=64 features, K=32 topk,
// E = N*16 edges. D==64 is the whole design: one wave per node, lane l owns
// feature column l.

#define DFEAT 64
#define KTOP  32

// Kernel A: reconstruct dense[N,64] from top-k compressed (values, indices).
// One wave per node. Lanes 0..31 each load one (idx, val) pair; broadcast all
// 32 pairs via shfl and accumulate into the owning lane. Duplicate indices
// within a row accumulate correctly (reference uses .at[].add).
__global__ __launch_bounds__(256) void build_dense_kernel(
    const float* __restrict__ topk_v,
    const int*   __restrict__ topk_i,
    float*       __restrict__ dense,
    int n_nodes)
{
    int wave = (blockIdx.x * blockDim.x + threadIdx.x) >> 6;
    int lane = threadIdx.x & 63;
    if (wave >= n_nodes) return;

    int   idx = -1;
    float val = 0.0f;
    if (lane < KTOP) {
        idx = topk_i[wave * KTOP + lane];
        val = topk_v[wave * KTOP + lane];
    }

    float acc = 0.0f;
#pragma unroll
    for (int k = 0; k < KTOP; ++k) {
        int   ik = __shfl(idx, k, 64);
        float vk = __shfl(val, k, 64);
        acc += (ik == lane) ? vk : 0.0f;
    }
    dense[wave * DFEAT + lane] = acc;
}

// Kernel B: CSR aggregation + GIN update. One wave per destination node.
// edge_dst is sorted, so each node's edge range comes from two binary
// searches (wave-uniform). edge_src entries for the range are loaded
// coalesced (64 at a time), broadcast by shfl, and each edge contributes a
// coalesced 256B row read from dense.
__global__ __launch_bounds__(256) void aggregate_kernel(
    const float* __restrict__ dense,
    const float* __restrict__ feat,
    const float* __restrict__ eps,
    const int*   __restrict__ edge_src,
    const int*   __restrict__ edge_dst,
    float*       __restrict__ out,
    int n_nodes, int n_edges)
{
    int wave = (blockIdx.x * blockDim.x + threadIdx.x) >> 6;
    int lane = threadIdx.x & 63;
    if (wave >= n_nodes) return;

    // lower_bound(edge_dst, wave)
    int lo = 0, hi = n_edges;
    while (lo < hi) {
        int mid = (lo + hi) >> 1;
        if (edge_dst[mid] < wave) lo = mid + 1; else hi = mid;
    }
    int start = lo;
    // upper_bound(edge_dst, wave), seeded at start
    hi = n_edges;
    while (lo < hi) {
        int mid = (lo + hi) >> 1;
        if (edge_dst[mid] <= wave) lo = mid + 1; else hi = mid;
    }
    int end = lo;

    float acc = 0.0f;
    for (int base = start; base < end; base += 64) {
        int n = end - base;
        if (n > 64) n = 64;
        int src = 0;
        if (lane < n) src = edge_src[base + lane];
        for (int j = 0; j < n; ++j) {
            int s = __shfl(src, j, 64);
            acc += dense[s * DFEAT + lane];
        }
    }

    float scale = 1.0f + eps[0];
    out[wave * DFEAT + lane] = scale * feat[wave * DFEAT + lane] + acc;
}

extern "C" void kernel_launch(void* const* d_in, const int* in_sizes, int n_in,
                              void* d_out, int out_size, void* d_ws, size_t ws_size,
                              hipStream_t stream)
{
    const float* feat     = (const float*)d_in[0];
    const float* topk_v   = (const float*)d_in[1];
    const float* eps      = (const float*)d_in[2];
    const int*   topk_i   = (const int*)d_in[3];
    const int*   edge_src = (const int*)d_in[4];
    const int*   edge_dst = (const int*)d_in[5];
    float*       out      = (float*)d_out;
    float*       dense    = (float*)d_ws;   // N*64 floats = 16 MB

    int n_nodes = in_sizes[0] / DFEAT;
    int n_edges = in_sizes[4];

    // 4 waves per 256-thread block, one wave per node.
    int blocks = (n_nodes + 3) / 4;
    build_dense_kernel<<<blocks, 256, 0, stream>>>(topk_v, topk_i, dense, n_nodes);
    aggregate_kernel<<<blocks, 256, 0, stream>>>(dense, feat, eps, edge_src,
                                                 edge_dst, out, n_nodes, n_edges);
}

// Round 3
// 145.816 us; speedup vs baseline: 2.0327x; 2.0327x over previous
//
#include <hip/hip_runtime.h>

// N=65536 nodes, D=64 feat, K=32 topk, E=N*16 edges (sorted edge_dst).
// Layout choices:
//  - build_dense: one wave per node, LDS row + ds atomic scatter (dup-safe).
//  - build_indptr: boundary detect over sorted edge_dst -> CSR indptr.
//  - aggregate: one wave per node; lane = (edge_slot 0..3)*16 + feature_quad
//    so each iteration gathers 8 edges as float4 rows (2KB/wave in flight),
//    then shfl_xor(16,32) folds the 4 edge slots into the full row.

#define DFEAT 64
#define KTOP  32

__global__ __launch_bounds__(256) void build_dense_kernel(
    const float* __restrict__ topk_v,
    const int*   __restrict__ topk_i,
    float*       __restrict__ dense,
    int n_nodes)
{
    __shared__ float rows[4][DFEAT];
    int wid  = threadIdx.x >> 6;
    int lane = threadIdx.x & 63;
    int wave = (blockIdx.x * blockDim.x + threadIdx.x) >> 6;
    bool active = wave < n_nodes;

    if (active) rows[wid][lane] = 0.0f;
    __syncthreads();
    if (active && lane < KTOP) {
        int   idx = topk_i[wave * KTOP + lane];
        float val = topk_v[wave * KTOP + lane];
        atomicAdd(&rows[wid][idx], val);   // LDS atomic; duplicates accumulate
    }
    __syncthreads();
    if (active) dense[(size_t)wave * DFEAT + lane] = rows[wid][lane];
}

// indptr[node] = first edge index with dst >= node; indptr[n_nodes] = n_edges.
__global__ __launch_bounds__(256) void build_indptr_kernel(
    const int* __restrict__ edge_dst,
    int*       __restrict__ indptr,
    int n_nodes, int n_edges)
{
    int e = blockIdx.x * blockDim.x + threadIdx.x;
    if (e >= n_edges) return;
    int cur  = edge_dst[e];
    int prev = (e == 0) ? -1 : edge_dst[e - 1];
    for (int node = prev + 1; node <= cur; ++node) indptr[node] = e;
    if (e == n_edges - 1) {
        for (int node = cur + 1; node <= n_nodes; ++node) indptr[node] = n_edges;
    }
}

__global__ __launch_bounds__(256) void aggregate_kernel(
    const float4* __restrict__ dense4,
    const float4* __restrict__ feat4,
    const float*  __restrict__ eps,
    const int*    __restrict__ edge_src,
    const int*    __restrict__ edge_dst,
    const int*    __restrict__ indptr,
    float4*       __restrict__ out4,
    int n_nodes, int n_edges)
{
    int wave = (blockIdx.x * blockDim.x + threadIdx.x) >> 6;
    int lane = threadIdx.x & 63;
    if (wave >= n_nodes) return;
    int f  = lane & 15;   // feature quad: floats [4f, 4f+4)
    int eg = lane >> 4;   // edge slot 0..3

    int start, end;
    if (indptr) {
        start = indptr[wave];
        end   = indptr[wave + 1];
    } else {
        // fallback: binary searches on sorted edge_dst (ws too small for indptr)
        int lo = 0, hi = n_edges;
        while (lo < hi) { int mid = (lo + hi) >> 1; if (edge_dst[mid] < wave) lo = mid + 1; else hi = mid; }
        start = lo; hi = n_edges;
        while (lo < hi) { int mid = (lo + hi) >> 1; if (edge_dst[mid] <= wave) lo = mid + 1; else hi = mid; }
        end = lo;
    }

    float4 acc = make_float4(0.f, 0.f, 0.f, 0.f);
    for (int base = start; base < end; base += 8) {
        int e0 = base + eg;
        int e1 = base + 4 + eg;
        if (e0 < end) {
            int s0 = edge_src[e0];                       // 16 lanes same addr: broadcast
            float4 r0 = dense4[(size_t)s0 * 16 + f];     // 16 lanes x 16B = 256B row
            acc.x += r0.x; acc.y += r0.y; acc.z += r0.z; acc.w += r0.w;
        }
        if (e1 < end) {
            int s1 = edge_src[e1];
            float4 r1 = dense4[(size_t)s1 * 16 + f];
            acc.x += r1.x; acc.y += r1.y; acc.z += r1.z; acc.w += r1.w;
        }
    }

    // fold the 4 edge slots: every lane ends with the full feature-quad sum
    acc.x += __shfl_xor(acc.x, 16, 64);
    acc.y += __shfl_xor(acc.y, 16, 64);
    acc.z += __shfl_xor(acc.z, 16, 64);
    acc.w += __shfl_xor(acc.w, 16, 64);
    acc.x += __shfl_xor(acc.x, 32, 64);
    acc.y += __shfl_xor(acc.y, 32, 64);
    acc.z += __shfl_xor(acc.z, 32, 64);
    acc.w += __shfl_xor(acc.w, 32, 64);

    if (eg == 0) {
        float  sc = 1.0f + eps[0];
        float4 ft = feat4[(size_t)wave * 16 + f];
        float4 o;
        o.x = sc * ft.x + acc.x;
        o.y = sc * ft.y + acc.y;
        o.z = sc * ft.z + acc.z;
        o.w = sc * ft.w + acc.w;
        out4[(size_t)wave * 16 + f] = o;
    }
}

extern "C" void kernel_launch(void* const* d_in, const int* in_sizes, int n_in,
                              void* d_out, int out_size, void* d_ws, size_t ws_size,
                              hipStream_t stream)
{
    const float* feat     = (const float*)d_in[0];
    const float* topk_v   = (const float*)d_in[1];
    const float* eps      = (const float*)d_in[2];
    const int*   topk_i   = (const int*)d_in[3];
    const int*   edge_src = (const int*)d_in[4];
    const int*   edge_dst = (const int*)d_in[5];
    float*       out      = (float*)d_out;

    int n_nodes = in_sizes[0] / DFEAT;
    int n_edges = in_sizes[4];

    float* dense = (float*)d_ws;                                  // 16 MB
    size_t dense_bytes = (size_t)n_nodes * DFEAT * sizeof(float);
    int*   indptr = nullptr;
    if (ws_size >= dense_bytes + (size_t)(n_nodes + 1) * sizeof(int))
        indptr = (int*)((char*)d_ws + dense_bytes);

    int node_blocks = (n_nodes + 3) / 4;  // 4 waves (nodes) per 256-thread block
    build_dense_kernel<<<node_blocks, 256, 0, stream>>>(topk_v, topk_i, dense, n_nodes);
    if (indptr) {
        int edge_blocks = (n_edges + 255) / 256;
        build_indptr_kernel<<<edge_blocks, 256, 0, stream>>>(edge_dst, indptr, n_nodes, n_edges);
    }
    aggregate_kernel<<<node_blocks, 256, 0, stream>>>(
        (const float4*)dense, (const float4*)feat, eps, edge_src, edge_dst,
        indptr, (float4*)out, n_nodes, n_edges);
}